// Round 5
// baseline (285.961 us; speedup 1.0000x reference)
//
#include <hip/hip_runtime.h>
#include <math.h>

#define NC 16
#define NBINS 15
#define NCELL (NC * NBINS)      // 240
#define GRID 1024
#define TPB 256
#define BLOCK_ELEMS 32768       // 1024 * 32768 = 33,554,432 exactly
#define NGROUP 16               // groups of 8 elems/thread -> 128 elems/thread
#define BROWS 2097152.0
#define MAXREP 8

// Kernel 1: per-thread private LDS histogram columns, TWO disjoint
// sub-histograms (even/odd elements) to break the RMW dependent chain.
// Layout: h[sub*4096 + bin*256 + col], col = threadIdx.x, 16 rows each
// (15 bins + dump row 15 for p==1.0). 32 KB LDS -> 4 blocks/CU (grid 1024).
// Packed cell: cnt[31:25] | t[24:18] | p_fix[17:0], p_fix = round(p*2048).
// Explicit 1-group-deep prefetch keeps ~16 scalar wave-loads in flight/wave.
__global__ void __launch_bounds__(256, 4) ece_partial(const float* __restrict__ logits,
                                                      const float* __restrict__ targets,
                                                      float* __restrict__ ws, int nrep) {
    __shared__ unsigned int h[2 * 16 * 256];   // 32 KB
#pragma unroll
    for (int r = 0; r < 32; ++r) h[r * 256 + threadIdx.x] = 0u;
    __syncthreads();

    const float LOG2E = 1.4426950408889634f;
    const int col  = threadIdx.x;
    const int base = blockIdx.x * BLOCK_ELEMS + threadIdx.x;  // class = tid & 15, every it

    float cl[8], ct[8], nl[8], nt_[8];
    // prologue: prefetch group 0 (it = 0..7, stride TPB elems)
#pragma unroll
    for (int j = 0; j < 8; ++j) {
        nl[j]  = logits[base + j * TPB];
        nt_[j] = targets[base + j * TPB];
    }

    for (int g = 0; g < NGROUP; ++g) {
#pragma unroll
        for (int j = 0; j < 8; ++j) { cl[j] = nl[j]; ct[j] = nt_[j]; }
        if (g < NGROUP - 1) {
            int it0 = (g + 1) * 8;
#pragma unroll
            for (int j = 0; j < 8; ++j) {
                nl[j]  = logits[base + (it0 + j) * TPB];
                nt_[j] = targets[base + (it0 + j) * TPB];
            }
        }
        // 4 pairs; within a pair the two RMWs hit disjoint sub-histograms,
        // so their latencies overlap; pair q+1 reads issue right after pair
        // q writes (in-order DS pipe preserves RAW on same address).
#pragma unroll
        for (int q = 0; q < 4; ++q) {
            float x0 = cl[2 * q],     t0 = ct[2 * q];
            float x1 = cl[2 * q + 1], t1 = ct[2 * q + 1];
            float e0 = __builtin_amdgcn_exp2f(-x0 * LOG2E);
            float e1 = __builtin_amdgcn_exp2f(-x1 * LOG2E);
            float p0 = __builtin_amdgcn_rcpf(1.0f + e0);
            float p1 = __builtin_amdgcn_rcpf(1.0f + e1);
            int b0 = ((int)(p0 * 15.0f)) & 15;   // p==1 -> row 15 (dump)
            int b1 = ((int)(p1 * 15.0f)) & 15;
            unsigned int v0 = (1u << 25) | (((unsigned int)t0) << 18) |
                              (unsigned int)(p0 * 2048.0f + 0.5f);
            unsigned int v1 = (1u << 25) | (((unsigned int)t1) << 18) |
                              (unsigned int)(p1 * 2048.0f + 0.5f);
            int a0 = b0 * 256 + col;
            int a1 = 4096 + b1 * 256 + col;
            unsigned int u0 = h[a0];
            unsigned int u1 = h[a1];
            h[a0] = u0 + v0;
            h[a1] = u1 + v1;
        }
    }
    __syncthreads();

    // Flush: thread idx < 240 owns cell (class = idx&15, bin = idx>>4);
    // reduce its 16 columns across both sub-histograms, 3 atomics to replica.
    int idx = threadIdx.x;
    if (idx < NCELL) {
        int cls = idx & 15, bin = idx >> 4;
        unsigned int cnt = 0, tsum = 0, psum = 0;
#pragma unroll
        for (int s = 0; s < 2; ++s) {
            int rowb = s * 4096 + bin * 256 + cls;
#pragma unroll
            for (int k = 0; k < 16; ++k) {
                unsigned int v = h[rowb + 16 * k];
                cnt  += v >> 25;
                tsum += (v >> 18) & 127u;
                psum += v & 0x3FFFFu;
            }
        }
        float* r = ws + (blockIdx.x & (nrep - 1)) * (3 * NCELL);
        atomicAdd(&r[idx],             (float)cnt);
        atomicAdd(&r[NCELL + idx],     (float)psum * (1.0f / 2048.0f));
        atomicAdd(&r[2 * NCELL + idx], (float)tsum);
    }
}

// Kernel 2: sum replicas, 240-cell epilogue -> scalar, double precision.
__global__ void __launch_bounds__(256) ece_final(const float* __restrict__ ws,
                                                 float* __restrict__ out, int nrep) {
    __shared__ double s_term[256];
    __shared__ int s_ne[256];
    int i = threadIdx.x;
    double term = 0.0;
    int ne = 0;
    if (i < NCELL) {
        float cnt = 0.0f, sp = 0.0f, st = 0.0f;
        for (int rep = 0; rep < nrep; ++rep) {
            const float* r = ws + rep * (3 * NCELL);
            cnt += r[i];
            sp  += r[NCELL + i];
            st  += r[2 * NCELL + i];
        }
        if (cnt > 0.0f) {
            ne = 1;
            term = fabs((double)sp / (double)cnt - (double)st / (double)cnt) *
                   ((double)cnt / BROWS);
        }
    }
    s_term[i] = term;
    s_ne[i] = ne;
    __syncthreads();
    for (int off = 128; off > 0; off >>= 1) {
        if (i < off) {
            s_term[i] += s_term[i + off];
            s_ne[i]   += s_ne[i + off];
        }
        __syncthreads();
    }
    if (i == 0) out[0] = (s_ne[0] > 0) ? (float)(s_term[0] / (double)s_ne[0]) : 0.0f;
}

extern "C" void kernel_launch(void* const* d_in, const int* in_sizes, int n_in,
                              void* d_out, int out_size, void* d_ws, size_t ws_size,
                              hipStream_t stream) {
    const float* logits  = (const float*)d_in[0];
    const float* targets = (const float*)d_in[1];
    float* ws  = (float*)d_ws;
    float* out = (float*)d_out;

    int nrep = MAXREP;
    while (nrep > 1 && (size_t)(nrep * 3 * NCELL * sizeof(float)) > ws_size) nrep >>= 1;

    hipMemsetAsync(ws, 0, nrep * 3 * NCELL * sizeof(float), stream);
    ece_partial<<<GRID, TPB, 0, stream>>>(logits, targets, ws, nrep);
    ece_final<<<1, 256, 0, stream>>>(ws, out, nrep);
}

// Round 6
// 277.645 us; speedup vs baseline: 1.0300x; 1.0300x over previous
//
#include <hip/hip_runtime.h>
#include <math.h>

#define NC 16
#define NBINS 15
#define NCELL (NC * NBINS)   // 240
#define GRID 2048
#define ITERS 64             // 33.5M / (2048*256)
#define BROWS 2097152.0      // B (rows)
#define MAXREP 8

// Kernel 1: per-thread private LDS histogram column, ONE class per thread
// (class = tid & 15 since thread-stride % 16 == 0). 16 rows (15 bins + dump
// row 15 for p==1.0) x 256 cols = 16 KB LDS -> 8 blocks/CU.
// ONE no-return ds_add_u32 per element (vs R4's read+write pair): addresses
// within a wave are always distinct (col = tid), so no serialization and no
// dependent chain. Packed: cnt[31:25] | t[24:18] | p_fix[17:0], p_fix=p*1024.
__global__ void __launch_bounds__(256, 8) ece_partial(const float* __restrict__ logits,
                                                      const float* __restrict__ targets,
                                                      float* __restrict__ ws, int nrep) {
    __shared__ unsigned int h[16 * 256];
#pragma unroll
    for (int r = 0; r < 16; ++r) h[r * 256 + threadIdx.x] = 0u;
    __syncthreads();

    const float LOG2E = 1.4426950408889634f;
    const int tid    = blockIdx.x * 256 + threadIdx.x;
    const int stride = GRID * 256;
    const int col    = threadIdx.x;

#define PROC(x, t)                                                        \
    {                                                                     \
        float e = __builtin_amdgcn_exp2f(-(x) * LOG2E);                   \
        float p = __builtin_amdgcn_rcpf(1.0f + e);                        \
        int b = ((int)(p * 15.0f)) & 15;   /* p==1 -> row 15 = dump */    \
        unsigned int pf = (unsigned int)(p * 1024.0f + 0.5f);             \
        unsigned int val = (1u << 25) | (((unsigned int)(t)) << 18) | pf; \
        atomicAdd(&h[b * 256 + col], val); /* ds_add_u32, no return */    \
    }

    for (int k = 0; k < ITERS; k += 4) {
        int i0 = tid + k * stride;
        int i1 = i0 + stride, i2 = i1 + stride, i3 = i2 + stride;
        float l0 = logits[i0], l1 = logits[i1], l2 = logits[i2], l3 = logits[i3];
        float t0 = targets[i0], t1 = targets[i1], t2 = targets[i2], t3 = targets[i3];
        PROC(l0, t0);
        PROC(l1, t1);
        PROC(l2, t2);
        PROC(l3, t3);
    }
#undef PROC
    __syncthreads();

    // Flush: thread idx < 240 owns cell (class = idx&15, bin = idx>>4),
    // reduces its 16 columns, then 3 atomics into replica blockIdx & (nrep-1).
    int idx = threadIdx.x;
    if (idx < NCELL) {
        int cls = idx & 15, bin = idx >> 4;
        int base = bin * 256 + cls;
        unsigned int cnt = 0, tsum = 0, psum = 0;
#pragma unroll
        for (int k = 0; k < 16; ++k) {
            unsigned int v = h[base + 16 * k];
            cnt  += v >> 25;
            tsum += (v >> 18) & 127u;
            psum += v & 0x3FFFFu;
        }
        float* r = ws + (blockIdx.x & (nrep - 1)) * (3 * NCELL);
        atomicAdd(&r[idx],             (float)cnt);
        atomicAdd(&r[NCELL + idx],     (float)psum * (1.0f / 1024.0f));
        atomicAdd(&r[2 * NCELL + idx], (float)tsum);
    }
}

// Kernel 2: sum replicas, 240-cell epilogue -> scalar, double precision.
__global__ void __launch_bounds__(256) ece_final(const float* __restrict__ ws,
                                                 float* __restrict__ out, int nrep) {
    __shared__ double s_term[256];
    __shared__ int s_ne[256];
    int i = threadIdx.x;
    double term = 0.0;
    int ne = 0;
    if (i < NCELL) {
        float cnt = 0.0f, sp = 0.0f, st = 0.0f;
        for (int rep = 0; rep < nrep; ++rep) {
            const float* r = ws + rep * (3 * NCELL);
            cnt += r[i];
            sp  += r[NCELL + i];
            st  += r[2 * NCELL + i];
        }
        if (cnt > 0.0f) {
            ne = 1;
            term = fabs((double)sp / (double)cnt - (double)st / (double)cnt) *
                   ((double)cnt / BROWS);
        }
    }
    s_term[i] = term;
    s_ne[i] = ne;
    __syncthreads();
    for (int off = 128; off > 0; off >>= 1) {
        if (i < off) {
            s_term[i] += s_term[i + off];
            s_ne[i]   += s_ne[i + off];
        }
        __syncthreads();
    }
    if (i == 0) out[0] = (s_ne[0] > 0) ? (float)(s_term[0] / (double)s_ne[0]) : 0.0f;
}

extern "C" void kernel_launch(void* const* d_in, const int* in_sizes, int n_in,
                              void* d_out, int out_size, void* d_ws, size_t ws_size,
                              hipStream_t stream) {
    const float* logits  = (const float*)d_in[0];
    const float* targets = (const float*)d_in[1];
    float* ws  = (float*)d_ws;
    float* out = (float*)d_out;

    int nrep = MAXREP;
    while (nrep > 1 && (size_t)(nrep * 3 * NCELL * sizeof(float)) > ws_size) nrep >>= 1;

    hipMemsetAsync(ws, 0, nrep * 3 * NCELL * sizeof(float), stream);
    ece_partial<<<GRID, 256, 0, stream>>>(logits, targets, ws, nrep);
    ece_final<<<1, 256, 0, stream>>>(ws, out, nrep);
}